// Round 1
// baseline (1124.756 us; speedup 1.0000x reference)
//
#include <hip/hip_runtime.h>

#define H_DIM 1024
#define B_DIM 128
#define S_DIM 256
#define V_DIM 32000
#define E_DIM 512

typedef __bf16 bf16_t;
typedef bf16_t bf16x8 __attribute__((ext_vector_type(8)));
typedef bf16_t bf16x4 __attribute__((ext_vector_type(4)));
typedef float floatx4 __attribute__((ext_vector_type(4)));

#define BM 128
#define BN 64
#define BK 32
#define LDK (BK + 8)   // +8 bf16 pad -> 80B rows, 16B aligned, 2-way-max bank conflicts

__device__ inline float fast_tanh(float x) {
    x = fminf(fmaxf(x, -15.f), 15.f);
    float e = __expf(2.f * x);
    return (e - 1.f) / (e + 1.f);
}
__device__ inline float sigmoidf_(float x) { return 1.f / (1.f + __expf(-x)); }

// GEMM: C[m][n] = sum_k A[m][k] * B[n][k]  (both K-contiguous, "NT")
// B is a K-concat of two arrays split at splitB (splitB multiple of BK).
// MODE 0: C[m][n] = acc + bias1[n] + bias2[n]
// MODE 1 (scores): per element t = acc + bias1[n] + proj[m>>8][n];
//                  atomicAdd(scores[m], sum_n tanh(t)*Vw[n])
template <int MODE>
__global__ __launch_bounds__(256, 2) void gemm_bf16(
    const float* __restrict__ A, int lda,
    const float* __restrict__ B1, int ldb1,
    const float* __restrict__ B2, int ldb2, int splitB,
    int K,
    float* __restrict__ C, int ldc,
    const float* __restrict__ bias1, const float* __restrict__ bias2,
    const float* __restrict__ proj, const float* __restrict__ Vw,
    float* __restrict__ scores)
{
    __shared__ bf16_t As[BM][LDK];
    __shared__ bf16_t Bs[BN][LDK];

    const int tid  = threadIdx.x;
    const int wid  = tid >> 6;
    const int lane = tid & 63;
    const int m0 = blockIdx.y * BM;
    const int n0 = blockIdx.x * BN;

    const int wave_m = (wid & 1) * 64;
    const int wave_n = (wid >> 1) * 32;
    const int laneM  = lane & 15;
    const int laneK  = (lane >> 4) * 8;

    const int s_row = tid >> 3;       // 0..31
    const int s_k4  = (tid & 7) * 4;  // 0..28

    floatx4 acc[4][2];
#pragma unroll
    for (int i = 0; i < 4; i++)
#pragma unroll
        for (int j = 0; j < 2; j++) acc[i][j] = (floatx4)0.f;

    for (int k0 = 0; k0 < K; k0 += BK) {
        // stage A tile (BM x BK), fp32 -> bf16
#pragma unroll
        for (int p = 0; p < 4; p++) {
            int r = s_row + p * 32;
            float4 v = *(const float4*)(A + (size_t)(m0 + r) * lda + (k0 + s_k4));
            *(bf16x4*)(&As[r][s_k4]) =
                (bf16x4){(bf16_t)v.x, (bf16_t)v.y, (bf16_t)v.z, (bf16_t)v.w};
        }
        // stage B tile (BN x BK): whole tile lies on one side of splitB
        const float* Bp; size_t ldb; int kb;
        if (k0 < splitB) { Bp = B1; ldb = (size_t)ldb1; kb = k0 + s_k4; }
        else             { Bp = B2; ldb = (size_t)ldb2; kb = k0 - splitB + s_k4; }
#pragma unroll
        for (int p = 0; p < 2; p++) {
            int r = s_row + p * 32;
            float4 v = *(const float4*)(Bp + (size_t)(n0 + r) * ldb + kb);
            *(bf16x4*)(&Bs[r][s_k4]) =
                (bf16x4){(bf16_t)v.x, (bf16_t)v.y, (bf16_t)v.z, (bf16_t)v.w};
        }
        __syncthreads();

        bf16x8 af[4], bfb[2];
#pragma unroll
        for (int mt = 0; mt < 4; mt++)
            af[mt] = *(const bf16x8*)(&As[wave_m + mt * 16 + laneM][laneK]);
#pragma unroll
        for (int nt = 0; nt < 2; nt++)
            bfb[nt] = *(const bf16x8*)(&Bs[wave_n + nt * 16 + laneM][laneK]);
#pragma unroll
        for (int mt = 0; mt < 4; mt++)
#pragma unroll
            for (int nt = 0; nt < 2; nt++)
                acc[mt][nt] = __builtin_amdgcn_mfma_f32_16x16x32_bf16(
                    af[mt], bfb[nt], acc[mt][nt], 0, 0, 0);
        __syncthreads();
    }

    if (MODE == 0) {
#pragma unroll
        for (int mt = 0; mt < 4; mt++) {
            int mrow = m0 + wave_m + mt * 16 + (lane >> 4) * 4;
#pragma unroll
            for (int nt = 0; nt < 2; nt++) {
                int n = n0 + wave_n + nt * 16 + laneM;
                float bsum = (bias1 ? bias1[n] : 0.f) + (bias2 ? bias2[n] : 0.f);
#pragma unroll
                for (int r = 0; r < 4; r++)
                    C[(size_t)(mrow + r) * ldc + n] = acc[mt][nt][r] + bsum;
            }
        }
    } else {
        // scores epilogue: tanh-reduce across N, one atomic per row per n-tile
#pragma unroll
        for (int mt = 0; mt < 4; mt++) {
#pragma unroll
            for (int r = 0; r < 4; r++) {
                int m = m0 + wave_m + mt * 16 + (lane >> 4) * 4 + r;
                int b = m >> 8;  // S = 256
                float v = 0.f;
#pragma unroll
                for (int nt = 0; nt < 2; nt++) {
                    int n = n0 + wave_n + nt * 16 + laneM;
                    float t = acc[mt][nt][r] + bias1[n] + proj[(size_t)b * H_DIM + n];
                    v += fast_tanh(t) * Vw[n];
                }
#pragma unroll
                for (int off = 1; off < 16; off <<= 1) v += __shfl_xor(v, off, 64);
                if (laneM == 0) atomicAdd(&scores[m], v);
            }
        }
    }
}

__global__ void attn_softmax_kernel(const float* __restrict__ scores,
                                    float* __restrict__ attn_ws,
                                    float* __restrict__ attn_out) {
    __shared__ float red[256];
    int b = blockIdx.x, t = threadIdx.x;
    float v = scores[b * S_DIM + t];
    red[t] = v; __syncthreads();
    for (int off = 128; off > 0; off >>= 1) {
        if (t < off) red[t] = fmaxf(red[t], red[t + off]);
        __syncthreads();
    }
    float mx = red[0]; __syncthreads();
    float e = __expf(v - mx);
    red[t] = e; __syncthreads();
    for (int off = 128; off > 0; off >>= 1) {
        if (t < off) red[t] += red[t + off];
        __syncthreads();
    }
    float a = e / red[0];
    attn_ws[b * S_DIM + t] = a;
    attn_out[b * S_DIM + t] = a;
}

__global__ __launch_bounds__(512) void context_kernel(
    const float* __restrict__ enc, const float* __restrict__ attn,
    float* __restrict__ ctx) {
    __shared__ float a_s[S_DIM];
    int b = blockIdx.x, t = threadIdx.x;
    if (t < 256) a_s[t] = attn[b * S_DIM + t];
    __syncthreads();
    float acc0 = 0.f, acc1 = 0.f;
    const float* base = enc + (size_t)b * S_DIM * H_DIM;
    for (int s = 0; s < S_DIM; s++) {
        float a = a_s[s];
        acc0 += a * base[(size_t)s * H_DIM + t];
        acc1 += a * base[(size_t)s * H_DIM + t + 512];
    }
    ctx[b * H_DIM + t] = acc0;
    ctx[b * H_DIM + t + 512] = acc1;
}

__global__ void pack_x0_kernel(const int* __restrict__ tok,
                               const float* __restrict__ emb_table,
                               const float* __restrict__ ctx,
                               const float* __restrict__ hidden0,
                               float* __restrict__ x0) {
    int b = blockIdx.y;
    int k = blockIdx.x * 256 + threadIdx.x;  // 0..2559
    float v;
    if (k < E_DIM)               v = emb_table[(size_t)tok[b] * E_DIM + k];
    else if (k < E_DIM + H_DIM)  v = ctx[b * H_DIM + (k - E_DIM)];
    else                         v = hidden0[b * H_DIM + (k - E_DIM - H_DIM)];
    x0[(size_t)b * (E_DIM + 2 * H_DIM) + k] = v;
}

__global__ void pack2_kernel(const float* __restrict__ p1,
                             const float* __restrict__ p2,
                             float* __restrict__ x) {
    int b = blockIdx.y;
    int k = blockIdx.x * 256 + threadIdx.x;  // 0..2047
    float v = (k < H_DIM) ? p1[b * H_DIM + k] : p2[b * H_DIM + (k - H_DIM)];
    x[(size_t)b * (2 * H_DIM) + k] = v;
}

__global__ void lstm_cell_kernel(const float* __restrict__ gates,
                                 const float* __restrict__ c_in,
                                 float* __restrict__ h_ws,
                                 float* __restrict__ h_out,
                                 float* __restrict__ c_out) {
    int b = blockIdx.y;
    int n = blockIdx.x * 256 + threadIdx.x;  // 0..1023
    const float* g = gates + (size_t)b * 4 * H_DIM;
    float i  = sigmoidf_(g[n]);
    float f  = sigmoidf_(g[H_DIM + n]);
    float gg = fast_tanh(g[2 * H_DIM + n]);
    float o  = sigmoidf_(g[3 * H_DIM + n]);
    float c  = f * c_in[b * H_DIM + n] + i * gg;
    float h  = o * fast_tanh(c);
    h_ws[b * H_DIM + n] = h;
    h_out[b * H_DIM + n] = h;
    c_out[b * H_DIM + n] = c;
}

__global__ void log_softmax_kernel(float* logits_out) {
    __shared__ float red[256];
    int b = blockIdx.x, t = threadIdx.x;
    float* row = logits_out + (size_t)b * V_DIM;
    float mx = -1e30f;
    for (int v = t; v < V_DIM; v += 256) mx = fmaxf(mx, row[v]);
    red[t] = mx; __syncthreads();
    for (int off = 128; off > 0; off >>= 1) {
        if (t < off) red[t] = fmaxf(red[t], red[t + off]);
        __syncthreads();
    }
    mx = red[0]; __syncthreads();
    float s = 0.f;
    for (int v = t; v < V_DIM; v += 256) s += __expf(row[v] - mx);
    red[t] = s; __syncthreads();
    for (int off = 128; off > 0; off >>= 1) {
        if (t < off) red[t] += red[t + off];
        __syncthreads();
    }
    float lse = mx + __logf(red[0]);
    for (int v = t; v < V_DIM; v += 256) row[v] = row[v] - lse;  // in-place, safe per-thread
}

extern "C" void kernel_launch(void* const* d_in, const int* in_sizes, int n_in,
                              void* d_out, int out_size, void* d_ws, size_t ws_size,
                              hipStream_t stream) {
    const int*   tok    = (const int*)  d_in[0];
    const float* hidden = (const float*)d_in[1];
    const float* cell   = (const float*)d_in[2];
    const float* enc    = (const float*)d_in[3];
    const float* embt   = (const float*)d_in[4];
    const float* W1w    = (const float*)d_in[5];
    const float* W1b    = (const float*)d_in[6];
    const float* W2w    = (const float*)d_in[7];
    const float* W2b    = (const float*)d_in[8];
    const float* Vw     = (const float*)d_in[9];
    // d_in[10] V_b: cancels in softmax, unused
    const float* wih0 = (const float*)d_in[11];
    const float* whh0 = (const float*)d_in[12];
    const float* bih0 = (const float*)d_in[13];
    const float* bhh0 = (const float*)d_in[14];
    const float* wih1 = (const float*)d_in[15];
    const float* whh1 = (const float*)d_in[16];
    const float* bih1 = (const float*)d_in[17];
    const float* bhh1 = (const float*)d_in[18];
    const float* fcw  = (const float*)d_in[19];
    const float* fcb  = (const float*)d_in[20];

    float* out        = (float*)d_out;
    float* pred       = out;                                    // B*V
    float* out_hidden = out + (size_t)B_DIM * V_DIM;            // L*B*H
    float* out_cell   = out_hidden + 2 * B_DIM * H_DIM;         // L*B*H
    float* out_attn   = out_cell + 2 * B_DIM * H_DIM;           // B*S

    float* ws     = (float*)d_ws;
    float* proj   = ws;                  // 131072
    float* scores = proj + 131072;       // 32768
    float* attnw  = scores + 32768;      // 32768
    float* ctx    = attnw + 32768;       // 131072
    float* x0     = ctx + 131072;        // 327680
    float* gates  = x0 + 327680;         // 524288
    float* h0     = gates + 524288;      // 131072
    float* x1     = h0 + 131072;         // 262144
    float* h1     = x1 + 262144;         // 131072
    float* x2     = h1 + 131072;         // 262144  (total ~7.9 MB)

    hipMemsetAsync(scores, 0, 32768 * sizeof(float), stream);

    dim3 blk(256);
    // proj[b][h] = h_top @ W2^T + W2_b   (M=128,N=1024,K=1024)
    gemm_bf16<0><<<dim3(16, 1), blk, 0, stream>>>(
        hidden + B_DIM * H_DIM, H_DIM, W2w, H_DIM, nullptr, 0, 1024, 1024,
        proj, H_DIM, W2b, nullptr, nullptr, nullptr, nullptr);
    // scores[m] = sum_h tanh(enc@W1^T + W1_b + proj)*V_w   (M=32768,N=1024,K=1024)
    gemm_bf16<1><<<dim3(16, 256), blk, 0, stream>>>(
        enc, H_DIM, W1w, H_DIM, nullptr, 0, 1024, 1024,
        nullptr, 0, W1b, nullptr, proj, Vw, scores);
    attn_softmax_kernel<<<128, 256, 0, stream>>>(scores, attnw, out_attn);
    context_kernel<<<128, 512, 0, stream>>>(enc, attnw, ctx);
    pack_x0_kernel<<<dim3(10, 128), blk, 0, stream>>>(tok, embt, ctx, hidden, x0);
    // gates0 = [emb|ctx|h0_in] @ [w_ih0|w_hh0]^T + b_ih0 + b_hh0  (K=2560, split 1536)
    gemm_bf16<0><<<dim3(64, 1), blk, 0, stream>>>(
        x0, 2560, wih0, 1536, whh0, 1024, 1536, 2560,
        gates, 4096, bih0, bhh0, nullptr, nullptr, nullptr);
    lstm_cell_kernel<<<dim3(4, 128), blk, 0, stream>>>(
        gates, cell, h0, out_hidden, out_cell);
    pack2_kernel<<<dim3(8, 128), blk, 0, stream>>>(h0, hidden + B_DIM * H_DIM, x1);
    // gates1 = [h0|h1_in] @ [w_ih1|w_hh1]^T + biases  (K=2048, split 1024)
    gemm_bf16<0><<<dim3(64, 1), blk, 0, stream>>>(
        x1, 2048, wih1, 1024, whh1, 1024, 1024, 2048,
        gates, 4096, bih1, bhh1, nullptr, nullptr, nullptr);
    lstm_cell_kernel<<<dim3(4, 128), blk, 0, stream>>>(
        gates, cell + B_DIM * H_DIM, h1,
        out_hidden + B_DIM * H_DIM, out_cell + B_DIM * H_DIM);
    pack2_kernel<<<dim3(8, 128), blk, 0, stream>>>(h1, ctx, x2);
    // logits (into d_out pred region) = [h1|ctx] @ fc_w^T + fc_b  (M=128,N=32000,K=2048)
    gemm_bf16<0><<<dim3(500, 1), blk, 0, stream>>>(
        x2, 2048, fcw, 2048, nullptr, 0, 2048, 2048,
        pred, V_DIM, fcb, nullptr, nullptr, nullptr, nullptr);
    log_softmax_kernel<<<128, 256, 0, stream>>>(pred);
}

// Round 2
// 813.119 us; speedup vs baseline: 1.3833x; 1.3833x over previous
//
#include <hip/hip_runtime.h>

#define H_DIM 1024
#define B_DIM 128
#define S_DIM 256
#define V_DIM 32000
#define E_DIM 512

typedef __bf16 bf16_t;
typedef bf16_t bf16x8 __attribute__((ext_vector_type(8)));
typedef bf16_t bf16x4 __attribute__((ext_vector_type(4)));
typedef float floatx4 __attribute__((ext_vector_type(4)));

// 128x128 tile, BK=64, 4 waves in 2x2, each wave 64x64 (4x4 16x16x32 MFMA tiles)
#define BM 128
#define BN 128
#define BK 64
#define LDK (BK + 8)   // 144B rows

__device__ inline float fast_tanh(float x) {
    x = fminf(fmaxf(x, -15.f), 15.f);
    float e = __expf(2.f * x);
    return (e - 1.f) / (e + 1.f);
}
__device__ inline float sigmoidf_(float x) { return 1.f / (1.f + __expf(-x)); }

__device__ inline bf16x4 cvt4(float4 v) {
    return (bf16x4){(bf16_t)v.x, (bf16_t)v.y, (bf16_t)v.z, (bf16_t)v.w};
}

// C[m][n] = sum_k A[m][k] * B[n][k]  (NT). B is K-concat [B1|B2] split at splitB
// (splitB % 64 == 0). Each block covers K range [z*kChunk, min(K,(z+1)*kChunk)).
// MODE 0: C = acc + bias1 + bias2 (full K in one block)
// MODE 1: scores epilogue: atomicAdd(scores[m], sum_n tanh(acc+bias1[n]+proj[m>>8][n])*Vw[n])
// MODE 2: atomicAdd(C, acc + (z==0 ? bias1+bias2 : 0))  -- split-K partial
template <int MODE>
__global__ __launch_bounds__(256) void gemm2(
    const float* __restrict__ A, int lda,
    const float* __restrict__ B1, int ldb1,
    const float* __restrict__ B2, int ldb2, int splitB,
    int K, int kChunk,
    float* __restrict__ C, int ldc,
    const float* __restrict__ bias1, const float* __restrict__ bias2,
    const float* __restrict__ proj, const float* __restrict__ Vw,
    float* __restrict__ scores)
{
    __shared__ bf16_t As[BM][LDK];
    __shared__ bf16_t Bs[BN][LDK];

    const int tid  = threadIdx.x;
    const int wid  = tid >> 6;
    const int lane = tid & 63;
    const int m0 = blockIdx.y * BM;
    const int n0 = blockIdx.x * BN;

    const int wave_m = (wid & 1) * 64;
    const int wave_n = (wid >> 1) * 64;
    const int laneM  = lane & 15;
    const int laneK  = (lane >> 4) * 8;

    const int tk = (tid & 15) * 4;   // k-offset within tile, 0..60
    const int tr = tid >> 4;         // 0..15

    const int kStart = blockIdx.z * kChunk;
    const int kEnd   = min(K, kStart + kChunk);

    floatx4 acc[4][4];
#pragma unroll
    for (int i = 0; i < 4; i++)
#pragma unroll
        for (int j = 0; j < 4; j++) acc[i][j] = (floatx4)0.f;

    const float* Arow = A + (size_t)(m0 + tr) * lda + tk;

    for (int k0 = kStart; k0 < kEnd; k0 += BK) {
        // stage A tile (128 x 64), fp32 -> bf16
#pragma unroll
        for (int p = 0; p < 8; p++) {
            float4 v = *(const float4*)(Arow + (size_t)(p * 16) * lda + k0);
            *(bf16x4*)(&As[tr + p * 16][tk]) = cvt4(v);
        }
        // stage B tile (128 x 64); tile fully on one side of splitB
        const float* Bp; size_t ldb; int kb;
        if (k0 < splitB) { Bp = B1; ldb = (size_t)ldb1; kb = k0 + tk; }
        else             { Bp = B2; ldb = (size_t)ldb2; kb = k0 - splitB + tk; }
        const float* Brow = Bp + (size_t)(n0 + tr) * ldb + kb;
#pragma unroll
        for (int p = 0; p < 8; p++) {
            float4 v = *(const float4*)(Brow + (size_t)(p * 16) * ldb);
            *(bf16x4*)(&Bs[tr + p * 16][tk]) = cvt4(v);
        }
        __syncthreads();

#pragma unroll
        for (int kk = 0; kk < 2; kk++) {
            bf16x8 af[4], bfb[4];
#pragma unroll
            for (int mt = 0; mt < 4; mt++)
                af[mt] = *(const bf16x8*)(&As[wave_m + mt * 16 + laneM][kk * 32 + laneK]);
#pragma unroll
            for (int nt = 0; nt < 4; nt++)
                bfb[nt] = *(const bf16x8*)(&Bs[wave_n + nt * 16 + laneM][kk * 32 + laneK]);
#pragma unroll
            for (int mt = 0; mt < 4; mt++)
#pragma unroll
                for (int nt = 0; nt < 4; nt++)
                    acc[mt][nt] = __builtin_amdgcn_mfma_f32_16x16x32_bf16(
                        af[mt], bfb[nt], acc[mt][nt], 0, 0, 0);
        }
        __syncthreads();
    }

    if (MODE == 0 || MODE == 2) {
        const bool addb = (MODE == 0) || (blockIdx.z == 0);
#pragma unroll
        for (int mt = 0; mt < 4; mt++) {
            int mrow = m0 + wave_m + mt * 16 + (lane >> 4) * 4;
#pragma unroll
            for (int nt = 0; nt < 4; nt++) {
                int n = n0 + wave_n + nt * 16 + laneM;
                float bsum = 0.f;
                if (addb) bsum = (bias1 ? bias1[n] : 0.f) + (bias2 ? bias2[n] : 0.f);
#pragma unroll
                for (int r = 0; r < 4; r++) {
                    float val = acc[mt][nt][r] + bsum;
                    if (MODE == 0) C[(size_t)(mrow + r) * ldc + n] = val;
                    else           atomicAdd(&C[(size_t)(mrow + r) * ldc + n], val);
                }
            }
        }
    } else {
        // scores epilogue
#pragma unroll
        for (int mt = 0; mt < 4; mt++) {
#pragma unroll
            for (int r = 0; r < 4; r++) {
                int m = m0 + wave_m + mt * 16 + (lane >> 4) * 4 + r;
                int b = m >> 8;  // S = 256
                float v = 0.f;
#pragma unroll
                for (int nt = 0; nt < 4; nt++) {
                    int n = n0 + wave_n + nt * 16 + laneM;
                    float t = acc[mt][nt][r] + bias1[n] + proj[(size_t)b * H_DIM + n];
                    v += fast_tanh(t) * Vw[n];
                }
#pragma unroll
                for (int off = 1; off < 16; off <<= 1) v += __shfl_xor(v, off, 64);
                if (laneM == 0) atomicAdd(&scores[m], v);
            }
        }
    }
}

__global__ void attn_softmax_kernel(const float* __restrict__ scores,
                                    float* __restrict__ attn_ws,
                                    float* __restrict__ attn_out) {
    __shared__ float red[256];
    int b = blockIdx.x, t = threadIdx.x;
    float v = scores[b * S_DIM + t];
    red[t] = v; __syncthreads();
    for (int off = 128; off > 0; off >>= 1) {
        if (t < off) red[t] = fmaxf(red[t], red[t + off]);
        __syncthreads();
    }
    float mx = red[0]; __syncthreads();
    float e = __expf(v - mx);
    red[t] = e; __syncthreads();
    for (int off = 128; off > 0; off >>= 1) {
        if (t < off) red[t] += red[t + off];
        __syncthreads();
    }
    float a = e / red[0];
    attn_ws[b * S_DIM + t] = a;
    attn_out[b * S_DIM + t] = a;
}

// context[b][h] = sum_s attn[b][s]*enc[b][s][h]; writes into x0[:,512+h] and x2[:,1024+h]
__global__ __launch_bounds__(256) void context_kernel(
    const float* __restrict__ enc, const float* __restrict__ attn,
    float* __restrict__ x0, float* __restrict__ x2) {
    __shared__ float a_s[S_DIM];
    int b = blockIdx.y;
    int h = blockIdx.x * 256 + threadIdx.x;
    a_s[threadIdx.x] = attn[b * S_DIM + threadIdx.x];
    __syncthreads();
    const float* base = enc + (size_t)b * S_DIM * H_DIM + h;
    float acc0 = 0.f, acc1 = 0.f;
#pragma unroll 4
    for (int s = 0; s < S_DIM; s += 2) {
        acc0 += a_s[s]     * base[(size_t)s * H_DIM];
        acc1 += a_s[s + 1] * base[(size_t)(s + 1) * H_DIM];
    }
    float c = acc0 + acc1;
    x0[(size_t)b * 2560 + 512 + h]  = c;
    x2[(size_t)b * 2048 + 1024 + h] = c;
}

// emb -> x0[:, :512]; hidden[0] -> x0[:, 1536:2560]; hidden[1] -> x1[:, 1024:2048]
__global__ void pack_misc_kernel(const int* __restrict__ tok,
                                 const float* __restrict__ emb_table,
                                 const float* __restrict__ hidden,
                                 float* __restrict__ x0, float* __restrict__ x1) {
    int b = blockIdx.y;
    int k = blockIdx.x * 256 + threadIdx.x;  // 0..2559
    if (k < E_DIM)
        x0[(size_t)b * 2560 + k] = emb_table[(size_t)tok[b] * E_DIM + k];
    else if (k < E_DIM + H_DIM)
        x0[(size_t)b * 2560 + 1024 + k] = hidden[b * H_DIM + (k - E_DIM)];
    else
        x1[(size_t)b * 2048 + 1024 + (k - E_DIM - H_DIM)] =
            hidden[(size_t)B_DIM * H_DIM + b * H_DIM + (k - E_DIM - H_DIM)];
}

__global__ void lstm_cell_kernel(const float* __restrict__ gates,
                                 const float* __restrict__ c_in,
                                 float* __restrict__ hx, int hx_stride,
                                 float* __restrict__ h_out,
                                 float* __restrict__ c_out) {
    int b = blockIdx.y;
    int n = blockIdx.x * 256 + threadIdx.x;  // 0..1023
    const float* g = gates + (size_t)b * 4 * H_DIM;
    float i  = sigmoidf_(g[n]);
    float f  = sigmoidf_(g[H_DIM + n]);
    float gg = fast_tanh(g[2 * H_DIM + n]);
    float o  = sigmoidf_(g[3 * H_DIM + n]);
    float c  = f * c_in[b * H_DIM + n] + i * gg;
    float h  = o * fast_tanh(c);
    hx[(size_t)b * hx_stride + n] = h;
    h_out[b * H_DIM + n] = h;
    c_out[b * H_DIM + n] = c;
}

__global__ __launch_bounds__(1024) void log_softmax_kernel(float* logits) {
    __shared__ float red[1024];
    int b = blockIdx.x, t = threadIdx.x;
    float* row = logits + (size_t)b * V_DIM;
    float mx = -1e30f;
    for (int v = t; v < V_DIM; v += 1024) mx = fmaxf(mx, row[v]);
    red[t] = mx; __syncthreads();
    for (int off = 512; off > 0; off >>= 1) {
        if (t < off) red[t] = fmaxf(red[t], red[t + off]);
        __syncthreads();
    }
    mx = red[0]; __syncthreads();
    float s = 0.f;
    for (int v = t; v < V_DIM; v += 1024) s += __expf(row[v] - mx);
    red[t] = s; __syncthreads();
    for (int off = 512; off > 0; off >>= 1) {
        if (t < off) red[t] += red[t + off];
        __syncthreads();
    }
    float lse = mx + __logf(red[0]);
    for (int v = t; v < V_DIM; v += 1024) row[v] = row[v] - lse;
}

extern "C" void kernel_launch(void* const* d_in, const int* in_sizes, int n_in,
                              void* d_out, int out_size, void* d_ws, size_t ws_size,
                              hipStream_t stream) {
    const int*   tok    = (const int*)  d_in[0];
    const float* hidden = (const float*)d_in[1];
    const float* cell   = (const float*)d_in[2];
    const float* enc    = (const float*)d_in[3];
    const float* embt   = (const float*)d_in[4];
    const float* W1w    = (const float*)d_in[5];
    const float* W1b    = (const float*)d_in[6];
    const float* W2w    = (const float*)d_in[7];
    const float* W2b    = (const float*)d_in[8];
    const float* Vw     = (const float*)d_in[9];
    // d_in[10] V_b cancels in softmax
    const float* wih0 = (const float*)d_in[11];
    const float* whh0 = (const float*)d_in[12];
    const float* bih0 = (const float*)d_in[13];
    const float* bhh0 = (const float*)d_in[14];
    const float* wih1 = (const float*)d_in[15];
    const float* whh1 = (const float*)d_in[16];
    const float* bih1 = (const float*)d_in[17];
    const float* bhh1 = (const float*)d_in[18];
    const float* fcw  = (const float*)d_in[19];
    const float* fcb  = (const float*)d_in[20];

    float* out        = (float*)d_out;
    float* pred       = out;
    float* out_hidden = out + (size_t)B_DIM * V_DIM;
    float* out_cell   = out_hidden + 2 * B_DIM * H_DIM;
    float* out_attn   = out_cell + 2 * B_DIM * H_DIM;

    float* ws     = (float*)d_ws;
    float* scores = ws;                   // 32768   (zeroed)
    float* proj   = scores + 32768;       // 131072  (zeroed)
    float* gatesA = proj + 131072;        // 524288  (zeroed)
    float* gatesB = gatesA + 524288;      // 524288  (zeroed)
    float* attnw  = gatesB + 524288;      // 32768
    float* x0     = attnw + 32768;        // 327680  [emb|ctx|h0_in] stride 2560
    float* x1     = x0 + 327680;          // 262144  [h0|h1_in] stride 2048
    float* x2     = x1 + 262144;          // 262144  [h1|ctx]   stride 2048

    // zero scores + proj + gatesA + gatesB in one shot
    hipMemsetAsync(ws, 0, (size_t)(32768 + 131072 + 2 * 524288) * sizeof(float), stream);

    dim3 blk(256);
    pack_misc_kernel<<<dim3(10, B_DIM), blk, 0, stream>>>(tok, embt, hidden, x0, x1);

    // proj = h_top @ W2^T + W2_b   (M=128,N=1024,K=1024) split-K=2, atomic
    gemm2<2><<<dim3(8, 1, 2), blk, 0, stream>>>(
        hidden + (size_t)B_DIM * H_DIM, H_DIM, W2w, H_DIM, nullptr, 0, H_DIM,
        H_DIM, 512, proj, H_DIM, W2b, nullptr, nullptr, nullptr, nullptr);

    // scores[m] = sum_n tanh(enc@W1^T + W1_b + proj)*Vw   (M=32768,N=1024,K=1024)
    gemm2<1><<<dim3(8, 256, 1), blk, 0, stream>>>(
        enc, H_DIM, W1w, H_DIM, nullptr, 0, H_DIM,
        H_DIM, H_DIM, nullptr, 0, W1b, nullptr, proj, Vw, scores);

    attn_softmax_kernel<<<B_DIM, 256, 0, stream>>>(scores, attnw, out_attn);
    context_kernel<<<dim3(4, B_DIM), blk, 0, stream>>>(enc, attnw, x0, x2);

    // gates0 = x0 @ [wih0|whh0]^T + b  (M=128,N=4096,K=2560) split-K=4, atomic
    gemm2<2><<<dim3(32, 1, 4), blk, 0, stream>>>(
        x0, 2560, wih0, 1536, whh0, H_DIM, 1536,
        2560, 640, gatesA, 4096, bih0, bhh0, nullptr, nullptr, nullptr);
    lstm_cell_kernel<<<dim3(4, B_DIM), blk, 0, stream>>>(
        gatesA, cell, x1, 2048, out_hidden, out_cell);

    // gates1 = x1 @ [wih1|whh1]^T + b  (M=128,N=4096,K=2048) split-K=4, atomic
    gemm2<2><<<dim3(32, 1, 4), blk, 0, stream>>>(
        x1, 2048, wih1, H_DIM, whh1, H_DIM, H_DIM,
        2048, 512, gatesB, 4096, bih1, bhh1, nullptr, nullptr, nullptr);
    lstm_cell_kernel<<<dim3(4, B_DIM), blk, 0, stream>>>(
        gatesB, cell + (size_t)B_DIM * H_DIM, x2, 2048,
        out_hidden + (size_t)B_DIM * H_DIM, out_cell + (size_t)B_DIM * H_DIM);

    // logits = x2 @ fc_w^T + fc_b  (M=128,N=32000,K=2048) -> pred
    gemm2<0><<<dim3(250, 1, 1), blk, 0, stream>>>(
        x2, 2048, fcw, 2048, nullptr, 0, 2048,
        2048, 2048, pred, V_DIM, fcb, nullptr, nullptr, nullptr, nullptr);

    log_softmax_kernel<<<B_DIM, 1024, 0, stream>>>(pred);
}

// Round 3
// 776.050 us; speedup vs baseline: 1.4493x; 1.0478x over previous
//
#include <hip/hip_runtime.h>

#define H_DIM 1024
#define B_DIM 128
#define S_DIM 256
#define V_DIM 32000
#define E_DIM 512

typedef __bf16 bf16_t;
typedef bf16_t bf16x8 __attribute__((ext_vector_type(8)));
typedef bf16_t bf16x4 __attribute__((ext_vector_type(4)));
typedef float floatx4 __attribute__((ext_vector_type(4)));

#define BM 128
#define BN 128
#define BK 64
#define LDK (BK + 8)

__device__ inline float fast_tanh(float x) {
    x = fminf(fmaxf(x, -15.f), 15.f);
    float e = __expf(2.f * x);
    return (e - 1.f) / (e + 1.f);
}
__device__ inline float sigmoidf_(float x) { return 1.f / (1.f + __expf(-x)); }
__device__ inline bf16x4 cvt4(float4 v) {
    return (bf16x4){(bf16_t)v.x, (bf16_t)v.y, (bf16_t)v.z, (bf16_t)v.w};
}
__device__ __forceinline__ void gload16(const bf16_t* g, bf16_t* l) {
    __builtin_amdgcn_global_load_lds(
        (const __attribute__((address_space(1))) void*)g,
        (__attribute__((address_space(3))) void*)l, 16, 0, 0);
}

// ---------------- bf16-input scores GEMM (Path A) ----------------
// scores[m] += sum_n tanh( (A@B^T)[m][n] + bias1[n] + proj[m>>8][n] ) * Vw[n]
// A: (32768,1024) bf16 row-major; B: (1024,1024) bf16 row-major. BK=64.
// LDS rows = 64 bf16 = 128B = 8 x 16B chunks, XOR-swizzled: phys = logical ^ (row&7).
__global__ __launch_bounds__(256) void gemm_scores_bf16(
    const bf16_t* __restrict__ A, const bf16_t* __restrict__ B,
    const float* __restrict__ bias1, const float* __restrict__ proj,
    const float* __restrict__ Vw, float* __restrict__ scores)
{
    __shared__ bf16_t As[128 * 64];
    __shared__ bf16_t Bs[128 * 64];

    const int tid  = threadIdx.x;
    const int wid  = tid >> 6;
    const int lane = tid & 63;
    const int m0 = blockIdx.y * BM;
    const int n0 = blockIdx.x * BN;

    const int wave_m = (wid & 1) * 64;
    const int wave_n = (wid >> 1) * 64;
    const int laneM  = lane & 15;
    const int laneG  = lane >> 4;

    const int srow = lane >> 3;  // 0..7 (row within 8-row issue group)
    const int pc   = lane & 7;   // physical 16B chunk this lane fills

    floatx4 acc[4][4];
#pragma unroll
    for (int i = 0; i < 4; i++)
#pragma unroll
        for (int j = 0; j < 4; j++) acc[i][j] = (floatx4)0.f;

    for (int k0 = 0; k0 < H_DIM; k0 += BK) {
        // stage A: wave w covers rows w*32 .. w*32+31, 4 issues of 8 rows
#pragma unroll
        for (int i = 0; i < 4; i++) {
            int r  = wid * 32 + i * 8 + srow;
            int lc = pc ^ (r & 7);  // logical chunk fetched into phys slot pc
            gload16(A + (size_t)(m0 + r) * H_DIM + k0 + lc * 8,
                    As + (wid * 32 + i * 8) * 64);
        }
#pragma unroll
        for (int i = 0; i < 4; i++) {
            int r  = wid * 32 + i * 8 + srow;
            int lc = pc ^ (r & 7);
            gload16(B + (size_t)(n0 + r) * H_DIM + k0 + lc * 8,
                    Bs + (wid * 32 + i * 8) * 64);
        }
        __syncthreads();  // drains vmcnt -> LDS tiles ready

#pragma unroll
        for (int kk = 0; kk < 2; kk++) {
            bf16x8 af[4], bfb[4];
#pragma unroll
            for (int mt = 0; mt < 4; mt++) {
                int ra = wave_m + mt * 16 + laneM;
                int pa = (kk * 4 + laneG) ^ (ra & 7);
                af[mt] = *(const bf16x8*)(&As[ra * 64 + pa * 8]);
            }
#pragma unroll
            for (int nt = 0; nt < 4; nt++) {
                int rb = wave_n + nt * 16 + laneM;
                int pb = (kk * 4 + laneG) ^ (rb & 7);
                bfb[nt] = *(const bf16x8*)(&Bs[rb * 64 + pb * 8]);
            }
#pragma unroll
            for (int mt = 0; mt < 4; mt++)
#pragma unroll
                for (int nt = 0; nt < 4; nt++)
                    acc[mt][nt] = __builtin_amdgcn_mfma_f32_16x16x32_bf16(
                        af[mt], bfb[nt], acc[mt][nt], 0, 0, 0);
        }
        __syncthreads();
    }

#pragma unroll
    for (int mt = 0; mt < 4; mt++) {
#pragma unroll
        for (int r = 0; r < 4; r++) {
            int m = m0 + wave_m + mt * 16 + (lane >> 4) * 4 + r;
            int b = m >> 8;
            float v = 0.f;
#pragma unroll
            for (int nt = 0; nt < 4; nt++) {
                int n = n0 + wave_n + nt * 16 + laneM;
                float t = acc[mt][nt][r] + bias1[n] + proj[(size_t)b * H_DIM + n];
                v += fast_tanh(t) * Vw[n];
            }
#pragma unroll
            for (int off = 1; off < 16; off <<= 1) v += __shfl_xor(v, off, 64);
            if (laneM == 0) atomicAdd(&scores[m], v);
        }
    }
}

// ---------------- fp32-input GEMM with register-prefetch pipeline ----------------
// C[m][n] = sum_k A[m][k]*B[n][k]; B = K-concat [B1|B2] split at splitB (mult of 64).
// MODE 1: scores epilogue (fused tanh reduce, fp32 fallback path)
// MODE 2: atomicAdd(C, acc + (z==0 ? biases : 0))
// MODE 3: z==0 -> C = acc + biases ; z>0 -> Cpart[z-1] = acc  (no atomics)
template <int MODE>
__global__ __launch_bounds__(256) void gemm2(
    const float* __restrict__ A, int lda,
    const float* __restrict__ B1, int ldb1,
    const float* __restrict__ B2, int ldb2, int splitB,
    int K, int kChunk,
    float* __restrict__ C, int ldc,
    float* __restrict__ Cpart, long long partStride,
    const float* __restrict__ bias1, const float* __restrict__ bias2,
    const float* __restrict__ proj, const float* __restrict__ Vw,
    float* __restrict__ scores)
{
    __shared__ bf16_t As[BM][LDK];
    __shared__ bf16_t Bs[BN][LDK];

    const int tid  = threadIdx.x;
    const int wid  = tid >> 6;
    const int lane = tid & 63;
    const int m0 = blockIdx.y * BM;
    const int n0 = blockIdx.x * BN;

    const int wave_m = (wid & 1) * 64;
    const int wave_n = (wid >> 1) * 64;
    const int laneM  = lane & 15;
    const int laneK  = (lane >> 4) * 8;

    const int tk = (tid & 15) * 4;
    const int tr = tid >> 4;

    const int kStart = blockIdx.z * kChunk;
    const int kEnd   = min(K, kStart + kChunk);

    floatx4 acc[4][4];
#pragma unroll
    for (int i = 0; i < 4; i++)
#pragma unroll
        for (int j = 0; j < 4; j++) acc[i][j] = (floatx4)0.f;

    const float* Arow = A + (size_t)(m0 + tr) * lda + tk;

    float4 ar[8], br[8];
    auto loadA = [&](int k0) {
#pragma unroll
        for (int p = 0; p < 8; p++)
            ar[p] = *(const float4*)(Arow + (size_t)(p * 16) * lda + k0);
    };
    auto loadB = [&](int k0) {
        const float* Bp; size_t ldb; int kb;
        if (k0 < splitB) { Bp = B1; ldb = (size_t)ldb1; kb = k0 + tk; }
        else             { Bp = B2; ldb = (size_t)ldb2; kb = k0 - splitB + tk; }
        const float* Brow = Bp + (size_t)(n0 + tr) * ldb + kb;
#pragma unroll
        for (int p = 0; p < 8; p++)
            br[p] = *(const float4*)(Brow + (size_t)(p * 16) * ldb);
    };

    loadA(kStart); loadB(kStart);

    for (int k0 = kStart; k0 < kEnd; k0 += BK) {
#pragma unroll
        for (int p = 0; p < 8; p++) *(bf16x4*)(&As[tr + p * 16][tk]) = cvt4(ar[p]);
#pragma unroll
        for (int p = 0; p < 8; p++) *(bf16x4*)(&Bs[tr + p * 16][tk]) = cvt4(br[p]);
        __syncthreads();
        if (k0 + BK < kEnd) { loadA(k0 + BK); loadB(k0 + BK); }  // in flight across MFMA
#pragma unroll
        for (int kk = 0; kk < 2; kk++) {
            bf16x8 af[4], bfb[4];
#pragma unroll
            for (int mt = 0; mt < 4; mt++)
                af[mt] = *(const bf16x8*)(&As[wave_m + mt * 16 + laneM][kk * 32 + laneK]);
#pragma unroll
            for (int nt = 0; nt < 4; nt++)
                bfb[nt] = *(const bf16x8*)(&Bs[wave_n + nt * 16 + laneM][kk * 32 + laneK]);
#pragma unroll
            for (int mt = 0; mt < 4; mt++)
#pragma unroll
                for (int nt = 0; nt < 4; nt++)
                    acc[mt][nt] = __builtin_amdgcn_mfma_f32_16x16x32_bf16(
                        af[mt], bfb[nt], acc[mt][nt], 0, 0, 0);
        }
        __syncthreads();
    }

    if (MODE == 2 || MODE == 3) {
        const bool addb = (blockIdx.z == 0);
        float* dst = C;
        if (MODE == 3 && blockIdx.z > 0)
            dst = Cpart + (size_t)(blockIdx.z - 1) * partStride;
#pragma unroll
        for (int mt = 0; mt < 4; mt++) {
            int mrow = m0 + wave_m + mt * 16 + (lane >> 4) * 4;
#pragma unroll
            for (int nt = 0; nt < 4; nt++) {
                int n = n0 + wave_n + nt * 16 + laneM;
                float bsum = 0.f;
                if (addb) bsum = (bias1 ? bias1[n] : 0.f) + (bias2 ? bias2[n] : 0.f);
#pragma unroll
                for (int r = 0; r < 4; r++) {
                    float val = acc[mt][nt][r] + bsum;
                    if (MODE == 2) atomicAdd(&C[(size_t)(mrow + r) * ldc + n], val);
                    else           dst[(size_t)(mrow + r) * ldc + n] = val;
                }
            }
        }
    } else {  // MODE 1
#pragma unroll
        for (int mt = 0; mt < 4; mt++) {
#pragma unroll
            for (int r = 0; r < 4; r++) {
                int m = m0 + wave_m + mt * 16 + (lane >> 4) * 4 + r;
                int b = m >> 8;
                float v = 0.f;
#pragma unroll
                for (int nt = 0; nt < 4; nt++) {
                    int n = n0 + wave_n + nt * 16 + laneM;
                    float t = acc[mt][nt][r] + bias1[n] + proj[(size_t)b * H_DIM + n];
                    v += fast_tanh(t) * Vw[n];
                }
#pragma unroll
                for (int off = 1; off < 16; off <<= 1) v += __shfl_xor(v, off, 64);
                if (laneM == 0) atomicAdd(&scores[m], v);
            }
        }
    }
}

__global__ void convert_kernel(const float* __restrict__ src,
                               bf16_t* __restrict__ dst, int n4) {
    int i = blockIdx.x * blockDim.x + threadIdx.x;
    int stride = gridDim.x * blockDim.x;
    for (; i < n4; i += stride) {
        float4 v = ((const float4*)src)[i];
        ((bf16x4*)dst)[i] = cvt4(v);
    }
}

// fused softmax over scores + context reduce; writes attn out + ctx into x0,x2
template <typename T>
__global__ __launch_bounds__(256) void softmax_context_kernel(
    const T* __restrict__ enc, const float* __restrict__ scores,
    float* __restrict__ out_attn, float* __restrict__ x0, float* __restrict__ x2)
{
    __shared__ float red[256];
    __shared__ float a_s[256];
    int b = blockIdx.x, t = threadIdx.x;
    float v = scores[b * S_DIM + t];
    red[t] = v; __syncthreads();
    for (int off = 128; off > 0; off >>= 1) {
        if (t < off) red[t] = fmaxf(red[t], red[t + off]);
        __syncthreads();
    }
    float mx = red[0]; __syncthreads();
    float e = __expf(v - mx);
    red[t] = e; __syncthreads();
    for (int off = 128; off > 0; off >>= 1) {
        if (t < off) red[t] += red[t + off];
        __syncthreads();
    }
    float a = e / red[0];
    out_attn[b * S_DIM + t] = a;
    a_s[t] = a;
    __syncthreads();

    const T* base = enc + (size_t)b * S_DIM * H_DIM;
    float c0 = 0.f, c1 = 0.f, c2 = 0.f, c3 = 0.f;
#pragma unroll 4
    for (int s = 0; s < S_DIM; s++) {
        float aw = a_s[s];
        const T* row = base + (size_t)s * H_DIM + t;
        c0 += aw * (float)row[0];
        c1 += aw * (float)row[256];
        c2 += aw * (float)row[512];
        c3 += aw * (float)row[768];
    }
    x0[(size_t)b * 2560 + 512 + t]        = c0;
    x0[(size_t)b * 2560 + 512 + t + 256]  = c1;
    x0[(size_t)b * 2560 + 512 + t + 512]  = c2;
    x0[(size_t)b * 2560 + 512 + t + 768]  = c3;
    x2[(size_t)b * 2048 + 1024 + t]       = c0;
    x2[(size_t)b * 2048 + 1024 + t + 256] = c1;
    x2[(size_t)b * 2048 + 1024 + t + 512] = c2;
    x2[(size_t)b * 2048 + 1024 + t + 768] = c3;
}

__global__ void pack_misc_kernel(const int* __restrict__ tok,
                                 const float* __restrict__ emb_table,
                                 const float* __restrict__ hidden,
                                 float* __restrict__ x0, float* __restrict__ x1) {
    int b = blockIdx.y;
    int k = blockIdx.x * 256 + threadIdx.x;
    if (k < E_DIM)
        x0[(size_t)b * 2560 + k] = emb_table[(size_t)tok[b] * E_DIM + k];
    else if (k < E_DIM + H_DIM)
        x0[(size_t)b * 2560 + 1024 + k] = hidden[b * H_DIM + (k - E_DIM)];
    else
        x1[(size_t)b * 2048 + 1024 + (k - E_DIM - H_DIM)] =
            hidden[(size_t)B_DIM * H_DIM + b * H_DIM + (k - E_DIM - H_DIM)];
}

__global__ void lstm_cell_kernel(const float* __restrict__ gates,
                                 const float* __restrict__ gpart, int nExtra,
                                 long long partStride,
                                 const float* __restrict__ c_in,
                                 float* __restrict__ hx, int hx_stride,
                                 float* __restrict__ h_out,
                                 float* __restrict__ c_out) {
    int b = blockIdx.y;
    int n = blockIdx.x * 256 + threadIdx.x;
    size_t base = (size_t)b * 4 * H_DIM;
    float gi = gates[base + n];
    float gf = gates[base + H_DIM + n];
    float gg = gates[base + 2 * H_DIM + n];
    float go = gates[base + 3 * H_DIM + n];
    for (int p = 0; p < nExtra; p++) {
        size_t pb = (size_t)p * partStride + base;
        gi += gpart[pb + n];
        gf += gpart[pb + H_DIM + n];
        gg += gpart[pb + 2 * H_DIM + n];
        go += gpart[pb + 3 * H_DIM + n];
    }
    float i = sigmoidf_(gi), f = sigmoidf_(gf), o = sigmoidf_(go);
    float g = fast_tanh(gg);
    float c = f * c_in[b * H_DIM + n] + i * g;
    float h = o * fast_tanh(c);
    hx[(size_t)b * hx_stride + n] = h;
    h_out[b * H_DIM + n] = h;
    c_out[b * H_DIM + n] = c;
}

__global__ __launch_bounds__(1024) void log_softmax_kernel(
    float* __restrict__ pred, const float* __restrict__ part) {
    __shared__ float red[1024];
    int b = blockIdx.x, t = threadIdx.x;
    float lv[32];
    float mx = -1e30f;
#pragma unroll
    for (int j = 0; j < 32; j++) {
        int v = t + j * 1024;
        float x = -1e30f;
        if (v < V_DIM) {
            x = pred[(size_t)b * V_DIM + v];
            if (part) x += part[(size_t)b * V_DIM + v];
        }
        lv[j] = x;
        mx = fmaxf(mx, x);
    }
    red[t] = mx; __syncthreads();
    for (int off = 512; off > 0; off >>= 1) {
        if (t < off) red[t] = fmaxf(red[t], red[t + off]);
        __syncthreads();
    }
    mx = red[0]; __syncthreads();
    float s = 0.f;
#pragma unroll
    for (int j = 0; j < 32; j++) s += __expf(lv[j] - mx);
    red[t] = s; __syncthreads();
    for (int off = 512; off > 0; off >>= 1) {
        if (t < off) red[t] += red[t + off];
        __syncthreads();
    }
    float lse = mx + __logf(red[0]);
#pragma unroll
    for (int j = 0; j < 32; j++) {
        int v = t + j * 1024;
        if (v < V_DIM) pred[(size_t)b * V_DIM + v] = lv[j] - lse;
    }
}

extern "C" void kernel_launch(void* const* d_in, const int* in_sizes, int n_in,
                              void* d_out, int out_size, void* d_ws, size_t ws_size,
                              hipStream_t stream) {
    const int*   tok    = (const int*)  d_in[0];
    const float* hidden = (const float*)d_in[1];
    const float* cell   = (const float*)d_in[2];
    const float* enc    = (const float*)d_in[3];
    const float* embt   = (const float*)d_in[4];
    const float* W1w    = (const float*)d_in[5];
    const float* W1b    = (const float*)d_in[6];
    const float* W2w    = (const float*)d_in[7];
    const float* W2b    = (const float*)d_in[8];
    const float* Vw     = (const float*)d_in[9];
    const float* wih0 = (const float*)d_in[11];
    const float* whh0 = (const float*)d_in[12];
    const float* bih0 = (const float*)d_in[13];
    const float* bhh0 = (const float*)d_in[14];
    const float* wih1 = (const float*)d_in[15];
    const float* whh1 = (const float*)d_in[16];
    const float* bih1 = (const float*)d_in[17];
    const float* bhh1 = (const float*)d_in[18];
    const float* fcw  = (const float*)d_in[19];
    const float* fcb  = (const float*)d_in[20];

    float* out        = (float*)d_out;
    float* pred       = out;
    float* out_hidden = out + (size_t)B_DIM * V_DIM;
    float* out_cell   = out_hidden + 2 * B_DIM * H_DIM;
    float* out_attn   = out_cell + 2 * B_DIM * H_DIM;

    // unified ws layout (float offsets)
    float* ws      = (float*)d_ws;
    float* scores  = ws;                      // 32768
    float* proj    = ws + 32768;              // 131072
    float* gatesA  = ws + 163840;             // 524288
    float* gatesB  = ws + 688128;             // 524288
    float* x0      = ws + 1212416;            // 327680
    float* x1      = ws + 1540096;            // 262144
    float* x2      = ws + 1802240;            // 262144
    float* gAp     = ws + 2064384;            // 3*524288   (A/B paths)
    float* gBp     = ws + 3637248;            // 3*524288
    float* fcpart  = ws + 5210112;            // 4096000
    bf16_t* encbf  = (bf16_t*)(ws + 9306112); // 33554432 bf16
    bf16_t* W1bf   = (bf16_t*)(ws + 26083328);// 1048576 bf16

    const bool pathA = ws_size >= (size_t)26607616 * 4;
    const bool pathB = !pathA && ws_size >= (size_t)9306112 * 4 + 16384000;
    const bool split = pathA || pathB;  // partial-buffer split-K available

    dim3 blk(256);

    if (split)
        hipMemsetAsync(ws, 0, (size_t)163840 * 4, stream);               // scores+proj
    else
        hipMemsetAsync(ws, 0, (size_t)1212416 * 4, stream);              // + gatesA/B

    pack_misc_kernel<<<dim3(10, B_DIM), blk, 0, stream>>>(tok, embt, hidden, x0, x1);

    // proj = h_top @ W2^T + W2_b (atomic split-K=2 into zeroed proj)
    gemm2<2><<<dim3(8, 1, 2), blk, 0, stream>>>(
        hidden + (size_t)B_DIM * H_DIM, H_DIM, W2w, H_DIM, nullptr, 0, H_DIM,
        H_DIM, 512, proj, H_DIM, nullptr, 0, W2b, nullptr, nullptr, nullptr, nullptr);

    if (pathA) {
        convert_kernel<<<4096, blk, 0, stream>>>(enc, encbf, 8388608);
        convert_kernel<<<1024, blk, 0, stream>>>(W1w, W1bf, 262144);
        gemm_scores_bf16<<<dim3(8, 256), blk, 0, stream>>>(
            encbf, W1bf, W1b, proj, Vw, scores);
        softmax_context_kernel<bf16_t><<<B_DIM, 256, 0, stream>>>(
            encbf, scores, out_attn, x0, x2);
    } else {
        gemm2<1><<<dim3(8, 256, 1), blk, 0, stream>>>(
            enc, H_DIM, W1w, H_DIM, nullptr, 0, H_DIM,
            H_DIM, H_DIM, nullptr, 0, nullptr, 0, W1b, nullptr, proj, Vw, scores);
        softmax_context_kernel<float><<<B_DIM, 256, 0, stream>>>(
            enc, scores, out_attn, x0, x2);
    }

    // gates0 = x0 @ [wih0|whh0]^T + b  (M=128,N=4096,K=2560)
    if (split) {
        gemm2<3><<<dim3(32, 1, 4), blk, 0, stream>>>(
            x0, 2560, wih0, 1536, whh0, H_DIM, 1536, 2560, 640,
            gatesA, 4096, gAp, 524288, bih0, bhh0, nullptr, nullptr, nullptr);
        lstm_cell_kernel<<<dim3(4, B_DIM), blk, 0, stream>>>(
            gatesA, gAp, 3, 524288, cell, x1, 2048, out_hidden, out_cell);
    } else {
        gemm2<2><<<dim3(32, 1, 4), blk, 0, stream>>>(
            x0, 2560, wih0, 1536, whh0, H_DIM, 1536, 2560, 640,
            gatesA, 4096, nullptr, 0, bih0, bhh0, nullptr, nullptr, nullptr);
        lstm_cell_kernel<<<dim3(4, B_DIM), blk, 0, stream>>>(
            gatesA, nullptr, 0, 0, cell, x1, 2048, out_hidden, out_cell);
    }

    // gates1 = x1 @ [wih1|whh1]^T + b  (M=128,N=4096,K=2048)
    if (split) {
        gemm2<3><<<dim3(32, 1, 4), blk, 0, stream>>>(
            x1, 2048, wih1, H_DIM, whh1, H_DIM, H_DIM, 2048, 512,
            gatesB, 4096, gBp, 524288, bih1, bhh1, nullptr, nullptr, nullptr);
        lstm_cell_kernel<<<dim3(4, B_DIM), blk, 0, stream>>>(
            gatesB, gBp, 3, 524288, cell + (size_t)B_DIM * H_DIM, x2, 2048,
            out_hidden + (size_t)B_DIM * H_DIM, out_cell + (size_t)B_DIM * H_DIM);
    } else {
        gemm2<2><<<dim3(32, 1, 4), blk, 0, stream>>>(
            x1, 2048, wih1, H_DIM, whh1, H_DIM, H_DIM, 2048, 512,
            gatesB, 4096, nullptr, 0, bih1, bhh1, nullptr, nullptr, nullptr);
        lstm_cell_kernel<<<dim3(4, B_DIM), blk, 0, stream>>>(
            gatesB, nullptr, 0, 0, cell + (size_t)B_DIM * H_DIM, x2, 2048,
            out_hidden + (size_t)B_DIM * H_DIM, out_cell + (size_t)B_DIM * H_DIM);
    }

    // logits = x2 @ fc_w^T + fc_b  (M=128,N=32000,K=2048)
    if (split) {
        gemm2<3><<<dim3(250, 1, 2), blk, 0, stream>>>(
            x2, 2048, fcw, 2048, nullptr, 0, 2048, 2048, 1024,
            pred, V_DIM, fcpart, 4096000, fcb, nullptr, nullptr, nullptr, nullptr);
        log_softmax_kernel<<<B_DIM, 1024, 0, stream>>>(pred, fcpart);
    } else {
        gemm2<3><<<dim3(250, 1, 1), blk, 0, stream>>>(
            x2, 2048, fcw, 2048, nullptr, 0, 2048, 2048, 2048,
            pred, V_DIM, nullptr, 0, fcb, nullptr, nullptr, nullptr, nullptr);
        log_softmax_kernel<<<B_DIM, 1024, 0, stream>>>(pred, nullptr);
    }
}